// Round 6
// baseline (2774.875 us; speedup 1.0000x reference)
//
#include <hip/hip_runtime.h>
#include <stdint.h>

#define Tn 100
#define Dn 51
#define Hn 128
#define G4 512     // 4*H
#define BR 8       // batch rows per workgroup
#define NWG 256    // workgroups (2048 / 8)
#define NTH 1024   // 16 waves (R5 lesson: 8 waves = 2/SIMD cannot hide the chain)
#define RP 264     // xhA row stride in bf16 elems (16B-aligned rows)
#define SLOTE 16384 // ring slot: one K-slice (32 tiles x 1KB) in u16 elems

typedef unsigned int uint32;
typedef unsigned short u16;
typedef short s16x8 __attribute__((ext_vector_type(8)));   // 8 bf16 = 4 VGPRs
typedef float f32x4v __attribute__((ext_vector_type(4)));

__device__ __forceinline__ float rcp_(float x){ return __builtin_amdgcn_rcpf(x); }
__device__ __forceinline__ float sigm(float x){ return rcp_(1.f + __expf(-x)); }
__device__ __forceinline__ float tanh_(float x){ return 1.f - 2.f*rcp_(1.f + __expf(2.f*x)); }

// fp32 -> bf16 round-to-nearest-even
__device__ __forceinline__ u16 f2bf(float f){
  uint32 u = __float_as_uint(f);
  return (u16)((u + 0x7fffu + ((u >> 16) & 1u)) >> 16);
}
__device__ __forceinline__ float bf2f(u16 u){ return __uint_as_float(((uint32)u)<<16); }

// A-fragment trick: row r (0..7) = bf16-hi of xh row r; row r+8 = bf16-lo.
// One MFMA computes both pumps; epilogue sums D[r] + D[r+8] via shfl.
__device__ __forceinline__ void wr_xh(u16* __restrict__ xhA, int r, int k, float v){
  u16 h = f2bf(v);
  xhA[r*RP + k]     = h;
  xhA[(r+8)*RP + k] = f2bf(v - bf2f(h));
}

struct WP {
  const float* W[6];   // [4H, din]  enc0..2, dec0..2 (fp32)
  const float* U[6];   // [4H, H]
  const float* Bb[6];  // [4H]
  const float* fW;     // [D, H]
  const float* fb;     // [D]
};

// ws: wsw = MFMA-B-fragment-swizzled bf16 weights.
// Layout per layer (uniform 131072 u16): chunk (n,s) at ((n*8+s)*64+lane)*8+j,
// holding Wc[k = s*32+(lane>>4)*8+j][c = n*16+(lane&15)], Wc = [Wih | Whh] along k,
// zero-padded (k>=K or s>=S). Chunk (n,s) is a contiguous 1KB = one wave's
// global_load_lds batch (64 lanes x 16B).
// fwt: [128][64] f32 (k-major, d minor, d>=51 pad 0) -- proj reads 64 consecutive
// floats per k across 64 lanes = conflict-free (R5's [d][132] layout was 8-way).
#define PREP_TOTAL (6*131072 + 6*512 + 8192 + 64)
__global__ void prep_kernel(WP p, u16* __restrict__ wsw, float* __restrict__ bias,
                            float* __restrict__ fwt, float* __restrict__ fbw)
{
  int gid = blockIdx.x*256 + threadIdx.x;
  if (gid >= PREP_TOTAL) return;
  if (gid < 6*131072){
    int l = gid >> 17;
    int e = gid & 131071;
    int n    = e >> 12;
    int s    = (e >> 9) & 7;
    int lane = (e >> 3) & 63;
    int j    = e & 7;
    int k = s*32 + (lane >> 4)*8 + j;
    int c = n*16 + (lane & 15);
    int din = (l % 3 == 0) ? Dn : Hn;
    int K = din + Hn;
    u16 v = 0;
    if (k < K){
      float f = (k < din) ? p.W[l][(size_t)c*din + k] : p.U[l][(size_t)c*Hn + (k - din)];
      v = f2bf(f);
    }
    wsw[gid] = v;
  } else if (gid < 6*131072 + 6*512){
    int i = gid - 6*131072;
    bias[i] = p.Bb[i>>9][i & 511];
  } else if (gid < 6*131072 + 6*512 + 8192){
    int i = gid - (6*131072 + 6*512);
    int k = i >> 6, d = i & 63;
    fwt[i] = (d < Dn) ? p.fW[(size_t)d*Hn + k] : 0.f;
  } else {
    int d = gid - (6*131072 + 6*512 + 8192);
    fbw[d] = (d < Dn) ? p.fb[d] : 0.f;
  }
}

// One 16B-per-lane async global->LDS batch = one (tile n, slice ts) 1KB chunk.
// LDS dest is wave-uniform base + lane*16 (m104); source is per-lane.
__device__ __forceinline__ void dma_tile(const u16* __restrict__ ws, u16* __restrict__ dslot,
                                         int n, int ts, int lane){
  const u16* g = ws + (((size_t)(n*8 + ts)) << 9) + (lane << 3);
  u16* l = dslot + (n << 9);
  __builtin_amdgcn_global_load_lds((const __attribute__((address_space(1))) uint32*)g,
                                   (__attribute__((address_space(3))) uint32*)l, 16, 0, 0);
}

// LDS-only barrier: drains DS ops, NEVER vmcnt -> weight DMAs stay in flight
// across phase boundaries. All cross-thread data in this kernel is LDS;
// 'out' stores are never read in-kernel.
__device__ __forceinline__ void bar_lds(){
  asm volatile("s_waitcnt lgkmcnt(0)" ::: "memory");
  __builtin_amdgcn_s_barrier();
}

// R2's gemm with the weight source swapped from global->VGPR to the LDS ring.
// Wave w owns tiles n0=2w, 2w+1; its ring chunks are per-wave PRIVATE, so the
// ring needs no barriers -- only per-wave counted waits:
//   sub-phase k: vmcnt(2)   [slice k landed; slice k+1 (2 loads) stays in flight]
//                ds_read A-frag + 2 B-frags from slot par
//                lgkmcnt(0) [reads returned before overwrite]
//                DMA slice k+2 -> slot par (just-freed; read again 2 phases on)
//                2 MFMAs; par ^= 1
// Boundary VMEM (src prefetch, proj out-stores) lands >=1 full phase before the
// vmcnt(2) that would over-drain it -> free. Ring parity `par` is a RUNNING
// counter threaded through all calls (R4 lesson: never restart per layer).
// C/D: col=lane&15, row=(lane>>4)*4+reg (m89) -> row r in lanes 0-31, r+8 in 32-63.
template<int S>
__device__ __forceinline__ void gemm_ring(u16* __restrict__ ring,
                                          const u16* __restrict__ xh_in,
                                          const u16* __restrict__ wsCur,
                                          const u16* __restrict__ wsNext,
                                          float bv0, float bv1,
                                          float* __restrict__ gates,
                                          int wave, int lane, int& par)
{
  const int mrow = lane & 15, kgrp = lane >> 4;
  const int n0 = wave*2;
  const int aoff = mrow*RP + (kgrp << 3);
  const int boff = (lane << 3);
  f32x4v acc0 = {0.f,0.f,0.f,0.f}, acc1 = {0.f,0.f,0.f,0.f};
  #pragma unroll
  for (int k=0; k<S; k++){
    asm volatile("s_waitcnt vmcnt(2)" ::: "memory");
    u16* sb = ring + par*SLOTE;
    s16x8 a  = *(const s16x8*)(xh_in + aoff + k*32);
    s16x8 b0 = *(const s16x8*)(sb + ((n0    ) << 9) + boff);
    s16x8 b1 = *(const s16x8*)(sb + ((n0 + 1) << 9) + boff);
    asm volatile("s_waitcnt lgkmcnt(0)" ::: "memory");
    __builtin_amdgcn_sched_barrier(0);
    {
      const int m = k + 2;
      const u16* wsx = (m < S) ? wsCur : wsNext;
      const int ts   = (m < S) ? m : (m - S);
      dma_tile(wsx, sb, n0,     ts, lane);
      dma_tile(wsx, sb, n0 + 1, ts, lane);
    }
    acc0 = __builtin_amdgcn_mfma_f32_16x16x32_bf16(a, b0, acc0, 0, 0, 0);
    acc1 = __builtin_amdgcn_mfma_f32_16x16x32_bf16(a, b1, acc1, 0, 0, 0);
    par ^= 1;
  }
  // fold lo-product rows (A rows 8-15, lanes 32-63) into hi rows (lanes 0-31)
  #pragma unroll
  for (int v=0; v<4; v++){
    float l0 = __shfl_down(acc0[v], 32);
    float l1 = __shfl_down(acc1[v], 32);
    acc0[v] += l0;
    acc1[v] += l1;
  }
  if (kgrp < 2){
    int rb = kgrp*4;
    int c0g = n0*16 + mrow, c1g = c0g + 16;
    #pragma unroll
    for (int v=0; v<4; v++){
      gates[(rb+v)*G4 + c0g] = acc0[v] + bv0;
      gates[(rb+v)*G4 + c1g] = acc1[v] + bv1;
    }
  }
}

// Fused activation: gates -> (h, c-in-REGISTER), h written straight into the
// A-tiles that consume it. Thread->(r,j) map is static, so c-state lives in one
// VGPR per layer per thread (frees 12 KB LDS for the ring).
__device__ __forceinline__ void activate2(const float* __restrict__ gates, float& cref,
                                          u16* __restrict__ xh_self, int din_self,
                                          u16* __restrict__ xh_next,
                                          float* __restrict__ h2S, int tid)
{
  int r = tid >> 7, j = tid & 127;       // 1024 threads = 8 rows x 128
  const float* g = gates + r*G4;
  float ig = sigm (g[j]);
  float fg = sigm (g[j + Hn]);
  float gg = tanh_(g[j + 2*Hn]);
  float og = sigm (g[j + 3*Hn]);
  cref = fg*cref + ig*gg;
  float hv = og*tanh_(cref);
  wr_xh(xh_self, r, din_self + j, hv);
  if (xh_next) wr_xh(xh_next, r, j, hv);
  if (h2S)     h2S[r*Hn + j] = hv;
}

// OUTPUT IS FP32. 8 rows x 64 cols = 512 work items; fwtS[k*64+d] reads are
// 64-consecutive-float per k = conflict-free. pred feeds xh0.x directly.
__device__ __forceinline__ void proj_out(const float* __restrict__ h2S,
                                         const float* __restrict__ fwtS,
                                         const float* __restrict__ fbwS,
                                         u16* __restrict__ xh0,
                                         float* __restrict__ out, long b0, int t, int tid)
{
  if (tid < 512){
    int r = tid >> 6, d = tid & 63;
    const float* h = h2S + r*Hn;
    float acc = 0.f;
    #pragma unroll 8
    for (int k=0;k<Hn;k++) acc += h[k] * fwtS[k*64 + d];
    if (d < Dn){
      float pv = acc + fbwS[d];
      out[((size_t)(b0+r)*Tn + (Tn-1-t))*Dn + d] = pv;
      wr_xh(xh0, r, d, pv);
    }
  }
}

// (1024, 4): 4 waves/EU -> VGPR cap 128 (R9/R11: never let this spill).
__global__ __launch_bounds__(NTH, 4) void lstm_kernel(
    const float* __restrict__ src, const u16* __restrict__ wsw,
    const float* __restrict__ bias, const float* __restrict__ fwt,
    const float* __restrict__ fbw, float* __restrict__ out)
{
  __shared__ __align__(16) u16   ring[2*SLOTE];   // 64 KB weight ring (2 slices)
  __shared__ __align__(16) u16   xhA[3*16*RP];    // 24.75 KB per-layer A-tiles
  __shared__ __align__(16) float gates[BR*G4];    // 16 KB
  __shared__ __align__(16) float fwtS[8192];      // 32 KB f32 (accuracy: keep f32)
  __shared__ __align__(16) float h2S[BR*Hn];      // 4 KB dec-l2 h for proj
  __shared__ __align__(16) float fbwS[64];        // 0.25 KB   (total ~141 KB)

  const int tid = threadIdx.x;
  const int wave = tid >> 6, lane = tid & 63;
  const long b0 = (long)blockIdx.x * BR;
  u16* xh0 = xhA;
  u16* xh1 = xhA + 16*RP;
  u16* xh2 = xhA + 32*RP;

  const u16* wsE0 = wsw;
  const u16* wsE1 = wsw + 1*131072;
  const u16* wsE2 = wsw + 2*131072;
  const u16* wsD0 = wsw + 3*131072;
  const u16* wsD1 = wsw + 4*131072;
  const u16* wsD2 = wsw + 5*131072;

  // persistent per-thread state: c for 3 layers (act mapping r=tid>>7,j=tid&127)
  float c0 = 0.f, c1 = 0.f, c2 = 0.f;
  // per-thread epilogue biases for columns c0g, c0g+16, all 6 layers (12 VGPRs)
  const int c0g = wave*32 + (lane & 15);
  #define LB(l,o) bias[(l)*G4 + c0g + (o)]
  float bE0a=LB(0,0), bE0b=LB(0,16), bE1a=LB(1,0), bE1b=LB(1,16);
  float bE2a=LB(2,0), bE2b=LB(2,16), bD0a=LB(3,0), bD0b=LB(3,16);
  float bD1a=LB(4,0), bD1b=LB(4,16), bD2a=LB(5,0), bD2b=LB(5,16);
  #undef LB

  // src(0) prefetch
  float sA = 0.f, sB = 0.f;
  { int kk = tid & 255;
    if (kk < Dn){ int r0 = tid >> 8;
      sA = src[((size_t)(b0+r0)*Tn + 0)*Dn + kk];
      sB = src[((size_t)(b0+r0+4)*Tn + 0)*Dn + kk]; } }

  // ---- init LDS (prologue may use full __syncthreads: no pipeline yet) ----
  for (int i=tid; i<8192; i+=NTH) fwtS[i] = fwt[i];
  if (tid < 64) fbwS[tid] = fbw[tid];
  for (int i=tid; i<3*16*RP; i+=NTH) xhA[i] = 0;   // pads stay 0 forever
  __syncthreads();
  { int kk = tid & 255;
    if (kk < Dn){ int r0 = tid >> 8;
      wr_xh(xh0, r0,   kk, sA);
      wr_xh(xh0, r0+4, kk, sB); } }                // src(0) -> xh0.x
  __syncthreads();                                 // drains all init VMEM too

  // prime ring: slices 0,1 of enc-l0 -> queue = [sl0(2), sl1(2)] per wave
  { const int n0 = wave*2;
    dma_tile(wsE0, ring,         n0,   0, lane);
    dma_tile(wsE0, ring,         n0+1, 0, lane);
    dma_tile(wsE0, ring + SLOTE, n0,   1, lane);
    dma_tile(wsE0, ring + SLOTE, n0+1, 1, lane);
  }
  int par = 0;   // running ring parity (R4 lesson: thread it, never restart)

  // ---------------- encoder: 6 lgkm-barriers per t ----------------
  for (int t=0;t<Tn;t++){
    int tn = (t < Tn-1) ? t+1 : Tn-1;
    { int kk = tid & 255;                          // src(t+1) -> regs
      if (kk < Dn){ int r0 = tid >> 8;
        sA = src[((size_t)(b0+r0)*Tn + tn)*Dn + kk];
        sB = src[((size_t)(b0+r0+4)*Tn + tn)*Dn + kk]; } }
    gemm_ring<6>(ring, xh0, wsE0, wsE1, bE0a, bE0b, gates, wave, lane, par);
    bar_lds();
    activate2(gates, c0, xh0, Dn, xh1, nullptr, tid);
    if (t < Tn-1){ int kk = tid & 255;             // xh0 idle during act-l0
      if (kk < Dn){ int r0 = tid >> 8;
        wr_xh(xh0, r0,   kk, sA);
        wr_xh(xh0, r0+4, kk, sB); } }
    bar_lds();

    gemm_ring<8>(ring, xh1, wsE1, wsE2, bE1a, bE1b, gates, wave, lane, par);
    bar_lds();
    activate2(gates, c1, xh1, Hn, xh2, nullptr, tid);
    bar_lds();

    gemm_ring<8>(ring, xh2, wsE2, (t < Tn-1) ? wsE0 : wsD0, bE2a, bE2b,
                 gates, wave, lane, par);
    bar_lds();
    activate2(gates, c2, xh2, Hn, nullptr, nullptr, tid);
    bar_lds();
  }

  // ---------------- decoder ----------------
  // xh*.h-parts + c regs carry enc-final state. Reset xh0.x to pred(-1)=0.
  { int r = tid >> 7, kk = tid & 127;
    if (kk < Dn){ xh0[r*RP + kk] = 0; xh0[(r+8)*RP + kk] = 0; } }
  bar_lds();

  for (int t=0;t<Tn;t++){
    gemm_ring<6>(ring, xh0, wsD0, wsD1, bD0a, bD0b, gates, wave, lane, par);
    bar_lds();
    activate2(gates, c0, xh0, Dn, xh1, nullptr, tid);
    bar_lds();

    gemm_ring<8>(ring, xh1, wsD1, wsD2, bD1a, bD1b, gates, wave, lane, par);
    bar_lds();
    activate2(gates, c1, xh1, Hn, xh2, nullptr, tid);
    bar_lds();

    gemm_ring<8>(ring, xh2, wsD2, wsD0, bD2a, bD2b, gates, wave, lane, par);
    bar_lds();
    activate2(gates, c2, xh2, Hn, nullptr, h2S, tid);
    bar_lds();

    proj_out(h2S, fwtS, fbwS, xh0, out, b0, t, tid);
    bar_lds();
  }
}

extern "C" void kernel_launch(void* const* d_in, const int* in_sizes, int n_in,
                              void* d_out, int out_size, void* d_ws, size_t ws_size,
                              hipStream_t stream)
{
  (void)in_sizes; (void)n_in; (void)out_size; (void)ws_size;
  const float* src = (const float*)d_in[0];
  WP p;
  for (int l=0;l<3;l++){
    p.W[l]    = (const float*)d_in[1  + 3*l];
    p.U[l]    = (const float*)d_in[2  + 3*l];
    p.Bb[l]   = (const float*)d_in[3  + 3*l];
    p.W[3+l]  = (const float*)d_in[10 + 3*l];
    p.U[3+l]  = (const float*)d_in[11 + 3*l];
    p.Bb[3+l] = (const float*)d_in[12 + 3*l];
  }
  p.fW = (const float*)d_in[19];
  p.fb = (const float*)d_in[20];

  // ws: wsw u16[786432] (1.5MB) | bias f32[3072] | fwt f32[8192] | fbw f32[64]
  u16*   wsw  = (u16*)d_ws;
  float* bias = (float*)((char*)d_ws + 6*131072*sizeof(u16));
  float* fwt  = bias + 6*512;
  float* fbw  = fwt + 8192;

  prep_kernel<<<(PREP_TOTAL + 255)/256, 256, 0, stream>>>(p, wsw, bias, fwt, fbw);
  lstm_kernel<<<NWG, NTH, 0, stream>>>(src, wsw, bias, fwt, fbw, (float*)d_out);
}